// Round 2
// baseline (566.219 us; speedup 1.0000x reference)
//
#include <hip/hip_runtime.h>

// MultipleMappings: out[b,s,e] = sum_d X[b,s,d] * W[lang[b],e,d], passthrough if lang<0
// B=64, S=4096, D=256, L=16. fp32 I/O, bf16 MFMA compute.
// Round 4: barrier-free, LDS-free streaming design (round-3 retry; fixed
// nontemporal-store vector type: must be clang ext_vector, not HIP float4).
//   - Memory-bound op (537 MB @ 6.3 TB/s = 85 us floor); previous LDS+barrier
//     staging structure serialized memory and compute -> 1.2 TB/s only.
//   - W is pre-packed (cvt kernel) into fragment-major bf16: for each lang,
//     [cg(8)][k16(16)][lane(64)][8 bf16] -- each MFMA B-fragment is a contiguous,
//     lane-ordered 1 KiB block => B-loads are perfectly coalesced dwordx4 from L2.
//   - A fragments loaded straight from global (lane-pair = contiguous 64B sector,
//     fully consumed; 4 waves/block read identical addresses -> L1/MSHR merge).
//   - No __syncthreads anywhere in the matmul path: each wave is an independent
//     load->pack->MFMA stream the compiler software-pipelines across K.

typedef __attribute__((ext_vector_type(8))) short bf16x8;
typedef __attribute__((ext_vector_type(16))) float f32x16;
typedef __attribute__((ext_vector_type(4))) float f32x4;   // native vector: legal for nontemporal builtin

#define S_DIM 4096
#define D_DIM 256
#define NT 256

// pack two fp32 -> two bf16 (lo in low half), round-to-nearest-even
static __device__ __forceinline__ unsigned int pack_bf2(float lo, float hi) {
    unsigned int a = __float_as_uint(lo), b = __float_as_uint(hi);
    a += 0x7fffu + ((a >> 16) & 1u);
    b += 0x7fffu + ((b >> 16) & 1u);
    return (a >> 16) | (b & 0xffff0000u);
}

// W fp32 [L][256 e][256 d] -> fragment-major bf16 Wb: [L][cg(8)][k16(16)][lane(64)][8]
// where lane = khalf*32 + lrow holds W[cg*32 + lrow][k16*16 + khalf*8 + j], j=0..7.
// This matches the mfma_f32_32x32x16_bf16 B-operand layout exactly.
__global__ void cvt_w_kernel(const float* __restrict__ w, unsigned short* __restrict__ wb) {
    int t = blockIdx.x * NT + threadIdx.x;        // 131072 threads, one B-fragment slot each
    int lane = t & 63;
    int k16  = (t >> 6) & 15;
    int cg   = (t >> 10) & 7;
    int lang = t >> 13;
    int lrow = lane & 31, khalf = lane >> 5;
    const float* src = w + (((size_t)(lang << 8) + (cg << 5) + lrow) << 8) + (k16 << 4) + (khalf << 3);
    f32x4 v0 = *(const f32x4*)src;
    f32x4 v1 = *(const f32x4*)(src + 4);
    union { bf16x8 v; unsigned int u[4]; } p;
    p.u[0] = pack_bf2(v0.x, v0.y);
    p.u[1] = pack_bf2(v0.z, v0.w);
    p.u[2] = pack_bf2(v1.x, v1.y);
    p.u[3] = pack_bf2(v1.z, v1.w);
    *(bf16x8*)(wb + (size_t)t * 8) = p.v;         // fully coalesced 16B store
}

__global__ __launch_bounds__(NT, 4) void MultipleMappings_5952824672291_kernel(
    const float* __restrict__ X, const unsigned short* __restrict__ Wb,
    const int* __restrict__ pair_id, float* __restrict__ Y)
{
    const int b = blockIdx.y;
    const long base = ((long)b * S_DIM + (long)blockIdx.x * 32) * D_DIM;
    const float* Xb = X + base;
    float* Yb = Y + base;
    const int lang = pair_id[b];
    const int t = threadIdx.x;

    if (lang < 0) {
        // passthrough: copy 32x256 fp32 tile, 8 float4 per thread
        #pragma unroll
        for (int i = 0; i < 8; ++i) {
            int f4 = t + i * NT;
            f32x4 v = *(const f32x4*)(Xb + (long)f4 * 4);
            __builtin_nontemporal_store(v, (f32x4*)(Yb + (long)f4 * 4));
        }
        return;
    }

    const int lane  = t & 63;
    const int wave  = t >> 6;      // 4 waves: wave owns cols [wave*64, wave*64+64)
    const int lrow  = lane & 31;
    const int khalf = lane >> 5;   // operand k = k16*16 + khalf*8 + j

    // This lane's A source: row (s) = lrow, starting at its khalf sub-chunk.
    const float* xrow = Xb + (long)lrow * D_DIM + khalf * 8;
    // B fragment streams for this wave's two 32-col tiles (cg = wave*2 + ct).
    const unsigned short* wl  = Wb + (size_t)lang * (8 * 16 * 64 * 8);
    const unsigned short* wt0 = wl + (size_t)(wave * 2 + 0) * (16 * 512) + lane * 8;
    const unsigned short* wt1 = wl + (size_t)(wave * 2 + 1) * (16 * 512) + lane * 8;

    f32x16 acc0 = {}, acc1 = {};

    #pragma unroll 4
    for (int k16 = 0; k16 < 16; ++k16) {
        // A: 8 consecutive fp32 of this lane's row -> bf16x8
        f32x4 a0 = *(const f32x4*)(xrow + k16 * 16);
        f32x4 a1 = *(const f32x4*)(xrow + k16 * 16 + 4);
        union { bf16x8 v; unsigned int u[4]; } af;
        af.u[0] = pack_bf2(a0.x, a0.y);
        af.u[1] = pack_bf2(a0.z, a0.w);
        af.u[2] = pack_bf2(a1.x, a1.y);
        af.u[3] = pack_bf2(a1.z, a1.w);
        // B: contiguous lane-ordered fragments, 16B/lane coalesced from L2
        bf16x8 b0 = *(const bf16x8*)(wt0 + (size_t)k16 * 512);
        bf16x8 b1 = *(const bf16x8*)(wt1 + (size_t)k16 * 512);
        acc0 = __builtin_amdgcn_mfma_f32_32x32x16_bf16(af.v, b0, acc0, 0, 0, 0);
        acc1 = __builtin_amdgcn_mfma_f32_32x32x16_bf16(af.v, b1, acc1, 0, 0, 0);
    }

    // C/D layout: col = lane&31, row = (reg&3) + 8*(reg>>2) + 4*khalf  [m74/m101]
    #pragma unroll
    for (int r = 0; r < 16; ++r) {
        int rowg = 4 * khalf + (r & 3) + 8 * (r >> 2);
        float* yr = Yb + (long)rowg * D_DIM + wave * 64 + lrow;
        __builtin_nontemporal_store(acc0[r], yr);
        __builtin_nontemporal_store(acc1[r], yr + 32);
    }
}

extern "C" void kernel_launch(void* const* d_in, const int* in_sizes, int n_in,
                              void* d_out, int out_size, void* d_ws, size_t ws_size,
                              hipStream_t stream) {
    const float* X   = (const float*)d_in[0];   // right_emb (64,4096,256) fp32
    const float* W   = (const float*)d_in[1];   // mapping (16,256,256) fp32
    const int*   pid = (const int*)d_in[2];     // pair_id (64,1) int32
    float*       Y   = (float*)d_out;
    unsigned short* Wbf = (unsigned short*)d_ws;  // 2 MiB fragment-major bf16 W

    cvt_w_kernel<<<dim3(512), dim3(NT), 0, stream>>>(W, Wbf);

    dim3 grid(S_DIM / 32, 64);   // (128, 64) = 8192 blocks, 256 thr, no LDS
    MultipleMappings_5952824672291_kernel<<<grid, dim3(NT), 0, stream>>>(X, Wbf, pid, Y);
}

// Round 3
// 450.281 us; speedup vs baseline: 1.2575x; 1.2575x over previous
//
#include <hip/hip_runtime.h>

// MultipleMappings: out[b,s,e] = sum_d X[b,s,d] * W[lang[b],e,d], passthrough if lang<0
// B=64, S=4096, D=256, L=16. fp32 I/O, bf16 MFMA compute.
// Round 5: hybrid of round-0 (DMA+LDS, main ~150us) and round-2 (fragment-major W).
//   - A (the 268 MB HBM stream) staged via global_load_lds DMA, DOUBLE-BUFFERED
//     with counted s_waitcnt vmcnt(4): next chunk's DMA stays in flight across the
//     barrier (T3/T4), removing round-0's full vmcnt(0) drain stall.
//   - W read directly from global in fragment-major bf16 (cvt kernel): each MFMA
//     B-fragment is a contiguous lane-ordered 1 KiB block, L2-resident (2 MiB).
//     Deletes round-0's 32 KiB ldsW + its DMA traffic.
//   - BM=64, each wave computes 64 rows x 64 cols => no B duplication in block,
//     acc = 4 x f32x16. LDS = 2 x 16 KiB A chunks only; 3 blocks/CU.
//   - Round-2 failure mode (VGPR_Count=32, serialized loads, 1.58 TB/s) avoided:
//     DMA gives MLP without VGPRs; A read once per block, not once per wave.

typedef __attribute__((ext_vector_type(8))) short bf16x8;
typedef __attribute__((ext_vector_type(16))) float f32x16;
typedef __attribute__((ext_vector_type(4))) float f32x4;

#define S_DIM 4096
#define D_DIM 256
#define BM 64
#define BK 64
#define NT 256

// pack two fp32 -> two bf16 (lo in low half), round-to-nearest-even
static __device__ __forceinline__ unsigned int pack_bf2(float lo, float hi) {
    unsigned int a = __float_as_uint(lo), b = __float_as_uint(hi);
    a += 0x7fffu + ((a >> 16) & 1u);
    b += 0x7fffu + ((b >> 16) & 1u);
    return (a >> 16) | (b & 0xffff0000u);
}

// 16-byte global -> LDS DMA. Dest is wave-uniform base + lane*16 (slot-ordered).
static __device__ __forceinline__ void dma16(const void* g, void* l) {
    __builtin_amdgcn_global_load_lds(
        (const __attribute__((address_space(1))) unsigned int*)g,
        (__attribute__((address_space(3))) unsigned int*)l, 16, 0, 0);
}

// W fp32 [L][256 e][256 d] -> fragment-major bf16 Wb: [L][cg(8)][k16(16)][lane(64)][8]
// lane = khalf*32 + lrow holds W[cg*32 + lrow][k16*16 + khalf*8 + j], j=0..7
// (exact mfma_f32_32x32x16_bf16 B-operand layout).
__global__ void cvt_w_kernel(const float* __restrict__ w, unsigned short* __restrict__ wb) {
    int t = blockIdx.x * NT + threadIdx.x;        // 131072 threads, one fragment slot each
    int lane = t & 63;
    int k16  = (t >> 6) & 15;
    int cg   = (t >> 10) & 7;
    int lang = t >> 13;
    int lrow = lane & 31, khalf = lane >> 5;
    const float* src = w + (((size_t)(lang << 8) + (cg << 5) + lrow) << 8) + (k16 << 4) + (khalf << 3);
    f32x4 v0 = *(const f32x4*)src;
    f32x4 v1 = *(const f32x4*)(src + 4);
    union { bf16x8 v; unsigned int u[4]; } p;
    p.u[0] = pack_bf2(v0.x, v0.y);
    p.u[1] = pack_bf2(v0.z, v0.w);
    p.u[2] = pack_bf2(v1.x, v1.y);
    p.u[3] = pack_bf2(v1.z, v1.w);
    *(bf16x8*)(wb + (size_t)t * 8) = p.v;
}

__global__ __launch_bounds__(NT, 3) void MultipleMappings_5952824672291_kernel(
    const float* __restrict__ X, const unsigned short* __restrict__ Wb,
    const int* __restrict__ pair_id, float* __restrict__ Y)
{
    // ldsA swizzle (byte offsets): (row, kg) -> row*256 + ((kg ^ (row&15)) * 16),
    // kg in [0,16) (4 fp32/group). DMA dest is linear slot*16; source is
    // inverse-swizzled (same involution) per guide rule 21. 2 x 16 KiB chunks.
    __shared__ float ldsA[2][BM * BK];

    const int b = blockIdx.y;
    const int t = threadIdx.x;
    const long base = ((long)b * S_DIM + (long)blockIdx.x * BM) * D_DIM;
    const float* Xb = X + base;
    float* Yb = Y + base;
    const int lang = pair_id[b];

    if (lang < 0) {
        // passthrough: copy 64x256 fp32 tile
        #pragma unroll
        for (int i = 0; i < 16; ++i) {
            int f4 = t + i * NT;
            f32x4 v = *(const f32x4*)(Xb + (long)f4 * 4);
            __builtin_nontemporal_store(v, (f32x4*)(Yb + (long)f4 * 4));
        }
        return;
    }

    const int lane  = t & 63;
    const int wave  = t >> 6;      // 4 waves: wave owns cols [wave*64, wave*64+64)
    const int lrow  = lane & 31;
    const int khalf = lane >> 5;   // operand k = k16*16 + khalf*8 + j

    // B fragment streams for this wave's two 32-col tiles (cg = wave*2 + ct).
    const unsigned short* wl  = Wb + (size_t)lang * (8 * 16 * 64 * 8);
    const unsigned short* wt0 = wl + (size_t)(wave * 2 + 0) * (16 * 512) + lane * 8;
    const unsigned short* wt1 = wl + (size_t)(wave * 2 + 1) * (16 * 512) + lane * 8;

    // A chunk stage: 64 rows x 64 d fp32 = 1024 16B slots; 4 DMA issues/thread.
    #define STAGE(buf, kc) do {                                                 \
        _Pragma("unroll")                                                       \
        for (int j = 0; j < 4; ++j) {                                           \
            int slot = j * NT + t;                                              \
            int row = slot >> 4, kgl = slot & 15;                               \
            int kgs = kgl ^ (row & 15);                                         \
            dma16(Xb + row * D_DIM + (kc) * BK + kgs * 4,                       \
                  (char*)ldsA[buf] + slot * 16);                                \
        }                                                                       \
    } while (0)

    f32x16 acc00 = {}, acc01 = {}, acc10 = {}, acc11 = {};

    STAGE(0, 0);
    #pragma unroll
    for (int kc = 0; kc < 4; ++kc) {
        const int cur = kc & 1;
        if (kc < 3) {
            STAGE(cur ^ 1, kc + 1);
            // 8 DMA outstanding (4 cur + 4 next); wait until only next's 4 remain.
            asm volatile("s_waitcnt vmcnt(4)" ::: "memory");
        } else {
            asm volatile("s_waitcnt vmcnt(0)" ::: "memory");
        }
        __builtin_amdgcn_s_barrier();   // raw: no vmcnt(0) drain, next DMA in flight
        const char* Ab = (const char*)ldsA[cur];
        #pragma unroll
        for (int kl = 0; kl < 4; ++kl) {
            const int k16 = kc * 4 + kl;
            bf16x8 b0 = *(const bf16x8*)(wt0 + (size_t)k16 * 512);
            bf16x8 b1 = *(const bf16x8*)(wt1 + (size_t)k16 * 512);
            const int g0 = kl * 4 + khalf * 2;
            // rows 0..31
            {
                const int row = lrow, m = row & 15;
                f32x4 a0 = *(const f32x4*)(Ab + row * 256 + ((g0 ^ m) * 16));
                f32x4 a1 = *(const f32x4*)(Ab + row * 256 + (((g0 + 1) ^ m) * 16));
                union { bf16x8 v; unsigned int u[4]; } af;
                af.u[0] = pack_bf2(a0.x, a0.y);
                af.u[1] = pack_bf2(a0.z, a0.w);
                af.u[2] = pack_bf2(a1.x, a1.y);
                af.u[3] = pack_bf2(a1.z, a1.w);
                acc00 = __builtin_amdgcn_mfma_f32_32x32x16_bf16(af.v, b0, acc00, 0, 0, 0);
                acc01 = __builtin_amdgcn_mfma_f32_32x32x16_bf16(af.v, b1, acc01, 0, 0, 0);
            }
            // rows 32..63
            {
                const int row = 32 + lrow, m = row & 15;
                f32x4 a0 = *(const f32x4*)(Ab + row * 256 + ((g0 ^ m) * 16));
                f32x4 a1 = *(const f32x4*)(Ab + row * 256 + (((g0 + 1) ^ m) * 16));
                union { bf16x8 v; unsigned int u[4]; } af;
                af.u[0] = pack_bf2(a0.x, a0.y);
                af.u[1] = pack_bf2(a0.z, a0.w);
                af.u[2] = pack_bf2(a1.x, a1.y);
                af.u[3] = pack_bf2(a1.z, a1.w);
                acc10 = __builtin_amdgcn_mfma_f32_32x32x16_bf16(af.v, b0, acc10, 0, 0, 0);
                acc11 = __builtin_amdgcn_mfma_f32_32x32x16_bf16(af.v, b1, acc11, 0, 0, 0);
            }
        }
        __builtin_amdgcn_s_barrier();   // all waves done reading buf before its reuse
    }

    // C/D layout: col = lane&31, row = (reg&3) + 8*(reg>>2) + 4*khalf  [m74/m101]
    #pragma unroll
    for (int r = 0; r < 16; ++r) {
        const int rowg = 4 * khalf + (r & 3) + 8 * (r >> 2);
        float* y0 = Yb + (long)rowg * D_DIM + wave * 64 + lrow;
        float* y1 = y0 + 32 * D_DIM;
        __builtin_nontemporal_store(acc00[r], y0);
        __builtin_nontemporal_store(acc01[r], y0 + 32);
        __builtin_nontemporal_store(acc10[r], y1);
        __builtin_nontemporal_store(acc11[r], y1 + 32);
    }
    #undef STAGE
}

extern "C" void kernel_launch(void* const* d_in, const int* in_sizes, int n_in,
                              void* d_out, int out_size, void* d_ws, size_t ws_size,
                              hipStream_t stream) {
    const float* X   = (const float*)d_in[0];   // right_emb (64,4096,256) fp32
    const float* W   = (const float*)d_in[1];   // mapping (16,256,256) fp32
    const int*   pid = (const int*)d_in[2];     // pair_id (64,1) int32
    float*       Y   = (float*)d_out;
    unsigned short* Wbf = (unsigned short*)d_ws;  // 2 MiB fragment-major bf16 W

    cvt_w_kernel<<<dim3(512), dim3(NT), 0, stream>>>(W, Wbf);

    dim3 grid(S_DIM / BM, 64);   // (64, 64) = 4096 blocks, 16/CU
    MultipleMappings_5952824672291_kernel<<<grid, dim3(NT), 0, stream>>>(X, Wbf, pid, Y);
}